// Round 1
// baseline (34007.654 us; speedup 1.0000x reference)
//
#include <hip/hip_runtime.h>

// ---------------------------------------------------------------------------
// Spiking VGG9 forward, 10 timesteps, batch 128, fp32.
// Baseline: direct 3x3 convs (LDS-staged input channel, register-tiled
// outputs), fused spike thresholding, separate avgpool, split-K FC1 GEMM.
// ---------------------------------------------------------------------------

#define LEAK_A 0.05f   // (1 - 0.95)
#define LEAK_B 0.95f

__global__ void zero_k(float* __restrict__ p, int n) {
    int i = blockIdx.x * blockDim.x + threadIdx.x;
    if (i < n) p[i] = 0.0f;
}

// mem0 = 0.05*mem0 + 0.95*static; spike = mem0 > 1; mem0 -= spike
__global__ void lif0_k(const float* __restrict__ stat, float* __restrict__ mem,
                       float* __restrict__ out, int n4) {
    int i = blockIdx.x * blockDim.x + threadIdx.x;
    if (i >= n4) return;
    float4 s = ((const float4*)stat)[i];
    float4 m = ((float4*)mem)[i];
    float4 o;
    m.x = LEAK_A * m.x + LEAK_B * s.x; o.x = (m.x > 1.0f) ? 1.0f : 0.0f; m.x -= o.x;
    m.y = LEAK_A * m.y + LEAK_B * s.y; o.y = (m.y > 1.0f) ? 1.0f : 0.0f; m.y -= o.y;
    m.z = LEAK_A * m.z + LEAK_B * s.z; o.z = (m.z > 1.0f) ? 1.0f : 0.0f; m.z -= o.z;
    m.w = LEAK_A * m.w + LEAK_B * s.w; o.w = (m.w > 1.0f) ? 1.0f : 0.0f; m.w -= o.w;
    ((float4*)mem)[i] = m;
    ((float4*)out)[i] = o;
}

// Direct 3x3 conv, stride 1 pad 1, NCHW / OIHW.
// Block = 256 threads. Each block: NIMG images, OC_TILE output channels,
// all H*W pixels. Per input channel: stage padded input (and OC_TILE*9
// weights) in LDS, accumulate in registers.
template <int CIN, int H, int W, int COUT, int OC_TILE, int NIMG, int PPT, bool SPIKE>
__global__ __launch_bounds__(256) void conv3x3_k(const float* __restrict__ in,
                                                 const float* __restrict__ wgt,
                                                 float* __restrict__ out) {
    constexpr int PH = H + 2, PW = W + 2;
    constexpr int TPR = W / PPT;        // threads per row
    constexpr int TPI = H * TPR;        // threads per image
    static_assert(NIMG * TPI == 256, "thread mapping mismatch");
    constexpr int TOT = NIMG * PH * PW;

    __shared__ float s_in[TOT];
    __shared__ float s_w[OC_TILE * 9];

    const int tid  = threadIdx.x;
    const int n0   = blockIdx.y * NIMG;
    const int oc0  = blockIdx.x * OC_TILE;
    const int img  = tid / TPI;
    const int rem  = tid % TPI;
    const int row  = rem / TPR;
    const int col0 = (rem % TPR) * PPT;

    float acc[OC_TILE][PPT];
#pragma unroll
    for (int oc = 0; oc < OC_TILE; ++oc)
#pragma unroll
        for (int p = 0; p < PPT; ++p) acc[oc][p] = 0.0f;

    for (int ic = 0; ic < CIN; ++ic) {
        __syncthreads();   // protect previous iteration's reads
        // stage padded input channel ic for NIMG images
        for (int e = tid; e < TOT; e += 256) {
            int im = e / (PH * PW);
            int r2 = e % (PH * PW);
            int pr = r2 / PW, pc = r2 % PW;
            int gr = pr - 1, gc = pc - 1;
            float v = 0.0f;
            if ((unsigned)gr < (unsigned)H && (unsigned)gc < (unsigned)W)
                v = in[(((size_t)(n0 + im) * CIN + ic) * H + gr) * W + gc];
            s_in[e] = v;
        }
        if (tid < OC_TILE * 9) {
            int oc = tid / 9, k = tid % 9;
            s_w[tid] = wgt[(((size_t)(oc0 + oc) * CIN + ic) * 9) + k];
        }
        __syncthreads();

        // load this thread's input window into registers
        float win[3][PPT + 2];
        const float* base = &s_in[img * PH * PW + row * PW + col0];
#pragma unroll
        for (int dr = 0; dr < 3; ++dr)
#pragma unroll
            for (int dc = 0; dc < PPT + 2; ++dc) win[dr][dc] = base[dr * PW + dc];

#pragma unroll
        for (int oc = 0; oc < OC_TILE; ++oc) {
            float w0 = s_w[oc * 9 + 0], w1 = s_w[oc * 9 + 1], w2 = s_w[oc * 9 + 2];
            float w3 = s_w[oc * 9 + 3], w4 = s_w[oc * 9 + 4], w5 = s_w[oc * 9 + 5];
            float w6 = s_w[oc * 9 + 6], w7 = s_w[oc * 9 + 7], w8 = s_w[oc * 9 + 8];
#pragma unroll
            for (int p = 0; p < PPT; ++p) {
                float a = acc[oc][p];
                a += w0 * win[0][p] + w1 * win[0][p + 1] + w2 * win[0][p + 2];
                a += w3 * win[1][p] + w4 * win[1][p + 1] + w5 * win[1][p + 2];
                a += w6 * win[2][p] + w7 * win[2][p + 1] + w8 * win[2][p + 2];
                acc[oc][p] = a;
            }
        }
    }

#pragma unroll
    for (int oc = 0; oc < OC_TILE; ++oc)
#pragma unroll
        for (int p = 0; p < PPT; ++p) {
            float v = acc[oc][p];
            if (SPIKE) v = (v > 1.0f) ? 1.0f : 0.0f;
            out[(((size_t)(n0 + img) * COUT + (oc0 + oc)) * H + row) * W + col0 + p] = v;
        }
}

// 2x2 avg pool (inputs are binary spikes -> sums exact)
template <int C, int H>
__global__ void pool_k(const float* __restrict__ in, float* __restrict__ out) {
    constexpr int HO = H / 2;
    int idx = blockIdx.x * 256 + threadIdx.x;
    constexpr int TOTAL = 128 * C * HO * HO;
    if (idx >= TOTAL) return;
    int w = idx % HO;
    int h = (idx / HO) % HO;
    int c = idx / (HO * HO);   // combined n*C + c
    const float* p = in + (size_t)c * H * H + (size_t)(2 * h) * H + 2 * w;
    out[idx] = (p[0] + p[1] + p[H] + p[H + 1]) * 0.25f;
}

// FC1 split-K partial GEMM: part[kt][n][j] = sum_{k in chunk kt} A[n][k]*W[j][k]
// A: [128][4096], W: [1024][4096], part: [8][128][1024]
__global__ __launch_bounds__(256) void fc1_partial_k(const float* __restrict__ A,
                                                     const float* __restrict__ Wt,
                                                     float* __restrict__ part) {
    const int jt = blockIdx.x, nt = blockIdx.y, kt = blockIdx.z;
    const int j0 = jt * 64, n0 = nt * 64, k0 = kt * 512;
    __shared__ float As[16][65];
    __shared__ float Ws[16][65];
    const int tid = threadIdx.x;
    const int tx = tid % 16, ty = tid / 16;

    float acc[4][4];
#pragma unroll
    for (int i = 0; i < 4; ++i)
#pragma unroll
        for (int j = 0; j < 4; ++j) acc[i][j] = 0.0f;

    for (int kk = k0; kk < k0 + 512; kk += 16) {
        __syncthreads();
        for (int e = tid; e < 1024; e += 256) {
            int n = e / 16, k = e % 16;
            As[k][n] = A[(size_t)(n0 + n) * 4096 + kk + k];
            Ws[k][n] = Wt[(size_t)(j0 + n) * 4096 + kk + k];
        }
        __syncthreads();
#pragma unroll
        for (int k = 0; k < 16; ++k) {
            float a[4], b[4];
#pragma unroll
            for (int i = 0; i < 4; ++i) a[i] = As[k][tx * 4 + i];
#pragma unroll
            for (int j = 0; j < 4; ++j) b[j] = Ws[k][ty * 4 + j];
#pragma unroll
            for (int i = 0; i < 4; ++i)
#pragma unroll
                for (int j = 0; j < 4; ++j) acc[i][j] += a[i] * b[j];
        }
    }
#pragma unroll
    for (int i = 0; i < 4; ++i)
#pragma unroll
        for (int j = 0; j < 4; ++j)
            part[((size_t)kt * 128 + n0 + tx * 4 + i) * 1024 + j0 + ty * 4 + j] = acc[i][j];
}

// reduce partials, LIF update for fc1, emit spikes
__global__ void fc1_reduce_k(const float* __restrict__ part, float* __restrict__ mem,
                             float* __restrict__ sbuf) {
    int idx = blockIdx.x * 256 + threadIdx.x;   // 131072 total
    float y = 0.0f;
#pragma unroll
    for (int kt = 0; kt < 8; ++kt) y += part[(size_t)kt * 131072 + idx];
    float m = mem[idx];
    m = LEAK_A * m + LEAK_B * y;
    float s = (m > 1.0f) ? 1.0f : 0.0f;
    m -= s;
    mem[idx] = m;
    sbuf[idx] = s;
}

// mem_fc2[n][o] += sum_j S[n][j] * W2[o][j]
__global__ __launch_bounds__(256) void fc2_k(const float* __restrict__ S,
                                             const float* __restrict__ W2,
                                             float* __restrict__ memfc2) {
    int n = blockIdx.x;
    int tid = threadIdx.x;
    __shared__ float red[10][256];
    float s0 = S[(size_t)n * 1024 + tid * 4 + 0];
    float s1 = S[(size_t)n * 1024 + tid * 4 + 1];
    float s2 = S[(size_t)n * 1024 + tid * 4 + 2];
    float s3 = S[(size_t)n * 1024 + tid * 4 + 3];
#pragma unroll
    for (int o = 0; o < 10; ++o) {
        const float* w = W2 + (size_t)o * 1024 + tid * 4;
        red[o][tid] = s0 * w[0] + s1 * w[1] + s2 * w[2] + s3 * w[3];
    }
    __syncthreads();
    for (int off = 128; off >= 1; off >>= 1) {
        if (tid < off) {
#pragma unroll
            for (int o = 0; o < 10; ++o) red[o][tid] += red[o][tid + off];
        }
        __syncthreads();
    }
    if (tid < 10) memfc2[n * 10 + tid] += red[tid][0];
}

__global__ void finalize_k(const float* __restrict__ memfc2, float* __restrict__ out, int n) {
    int i = blockIdx.x * blockDim.x + threadIdx.x;
    if (i < n) out[i] = memfc2[i] / 10.0f;
}

extern "C" void kernel_launch(void* const* d_in, const int* in_sizes, int n_in,
                              void* d_out, int out_size, void* d_ws, size_t ws_size,
                              hipStream_t stream) {
    const float* inp   = (const float*)d_in[0];
    const float* w1    = (const float*)d_in[1];
    const float* w2    = (const float*)d_in[2];
    const float* w3    = (const float*)d_in[3];
    const float* w4    = (const float*)d_in[4];
    const float* w5    = (const float*)d_in[5];
    const float* w6    = (const float*)d_in[6];
    const float* w7    = (const float*)d_in[7];
    const float* fc1w  = (const float*)d_in[8];
    const float* fc2w  = (const float*)d_in[9];
    float* out = (float*)d_out;

    float* ws = (float*)d_ws;
    size_t off = 0;
    float* stat  = ws + off; off += 8388608;            // conv1 output (static input)
    float* mem0  = ws + off; off += 8388608;            // LIF membrane, layer 1
    float* memf1 = ws + off; off += 131072;             // fc1 membrane
    float* memf2 = ws + off; off += 1280;               // fc2 membrane
    float* actA  = ws + off; off += 8388608;
    float* actB  = ws + off; off += 8388608;
    float* sbuf  = ws + off; off += 131072;             // fc1 spikes
    float* part  = ws + off; off += 1048576;            // fc1 split-K partials

    // zero the persistent membranes (mem0 | memf1 | memf2 are contiguous)
    {
        int n = 8388608 + 131072 + 1280;
        zero_k<<<(n + 255) / 256, 256, 0, stream>>>(mem0, n);
    }

    // static_input = conv1(inp)
    conv3x3_k<3, 32, 32, 64, 8, 2, 8, false>
        <<<dim3(8, 64), 256, 0, stream>>>(inp, w1, stat);

    for (int t = 0; t < 10; ++t) {
        lif0_k<<<8192, 256, 0, stream>>>(stat, mem0, actA, 2097152);

        conv3x3_k<64, 32, 32, 64, 8, 2, 8, true>
            <<<dim3(8, 64), 256, 0, stream>>>(actA, w2, actB);
        pool_k<64, 32><<<(128 * 64 * 16 * 16 + 255) / 256, 256, 0, stream>>>(actB, actA);

        conv3x3_k<64, 16, 16, 128, 8, 8, 8, true>
            <<<dim3(16, 16), 256, 0, stream>>>(actA, w3, actB);
        conv3x3_k<128, 16, 16, 128, 8, 8, 8, true>
            <<<dim3(16, 16), 256, 0, stream>>>(actB, w4, actA);
        pool_k<128, 16><<<(128 * 128 * 8 * 8 + 255) / 256, 256, 0, stream>>>(actA, actB);

        conv3x3_k<128, 8, 8, 256, 8, 16, 4, true>
            <<<dim3(32, 8), 256, 0, stream>>>(actB, w5, actA);
        conv3x3_k<256, 8, 8, 256, 8, 16, 4, true>
            <<<dim3(32, 8), 256, 0, stream>>>(actA, w6, actB);
        conv3x3_k<256, 8, 8, 256, 8, 16, 4, true>
            <<<dim3(32, 8), 256, 0, stream>>>(actB, w7, actA);
        pool_k<256, 8><<<(128 * 256 * 4 * 4 + 255) / 256, 256, 0, stream>>>(actA, actB);

        fc1_partial_k<<<dim3(16, 2, 8), 256, 0, stream>>>(actB, fc1w, part);
        fc1_reduce_k<<<512, 256, 0, stream>>>(part, memf1, sbuf);
        fc2_k<<<128, 256, 0, stream>>>(sbuf, fc2w, memf2);
    }

    finalize_k<<<(1280 + 255) / 256, 256, 0, stream>>>(memf2, out, 1280);
}

// Round 2
// 2970.584 us; speedup vs baseline: 11.4481x; 11.4481x over previous
//
#include <hip/hip_runtime.h>

// ---------------------------------------------------------------------------
// Spiking VGG9, 10 steps, B=128.  MFMA rewrite:
//  - activations NHWC bf16 (spikes are exact in bf16), spatially padded
//    buffers so 3x3 conv = 9 shift-GEMMs with zero masking
//  - weights 3-way bf16 split (hi/mid/lo): residual 2^-27 -> fp32-equivalent
//  - conv2..7 + fc1 on matrix cores (mfma_f32_16x16x32_bf16)
//  - conv1 / LIF membranes stay fp32
// ---------------------------------------------------------------------------

typedef __attribute__((ext_vector_type(8))) short short8v;
typedef __attribute__((ext_vector_type(4))) float f32x4;

__device__ __forceinline__ ushort f2bf(float f) {
    union { float f; unsigned u; } v; v.f = f;
    unsigned u = v.u;
    u += 0x7fffu + ((u >> 16) & 1u);   // RNE
    return (ushort)(u >> 16);
}
__device__ __forceinline__ float bf2f(ushort h) {
    union { unsigned u; float f; } v; v.u = ((unsigned)h) << 16;
    return v.f;
}
constexpr int ilog2(int x) { int r = 0; while (x > 1) { x >>= 1; ++r; } return r; }

// ---------------------------------------------------------------- zero ----
__global__ void zero4_k(float4* __restrict__ p, int n4) {
    int i = blockIdx.x * 256 + threadIdx.x;
    if (i < n4) p[i] = make_float4(0.f, 0.f, 0.f, 0.f);
}

// ------------------------------------------------------------ weight prep --
// conv weights OIHW fp32 -> [s][q][icb][oc][32ic] bf16, s in {hi,mid,lo}
template <int IC, int OC>
__global__ void prep_convw_k(const float* __restrict__ w, ushort* __restrict__ dst) {
    int idx = blockIdx.x * 256 + threadIdx.x;
    if (idx >= OC * IC * 9) return;
    int oc = idx / (IC * 9);
    int rem = idx % (IC * 9);
    int ic = rem / 9, q = rem % 9;
    float v = w[idx];
    ushort s0 = f2bf(v);
    float r1 = v - bf2f(s0);
    ushort s1 = f2bf(r1);
    float r2 = r1 - bf2f(s1);
    ushort s2 = f2bf(r2);
    constexpr int ICB = IC / 32;
    constexpr size_t SS = (size_t)9 * ICB * OC * 32;
    size_t b = ((size_t)q * ICB + ic / 32) * OC * 32 + (size_t)oc * 32 + (ic & 31);
    dst[b] = s0; dst[b + SS] = s1; dst[b + 2 * SS] = s2;
}

// fc1 weights [1024][4096] fp32, cols k=(c*16+h*4+w) -> k'=(h*4+w)*256+c,
// pack [s][kb(128)][j(1024)][32]
__global__ void prep_fc1w_k(const float* __restrict__ w, ushort* __restrict__ dst) {
    int idx = blockIdx.x * 256 + threadIdx.x;
    if (idx >= 1024 * 4096) return;
    int j = idx >> 12, k = idx & 4095;
    int c = k >> 4, hw = k & 15;
    int kp = hw * 256 + c;
    float v = w[idx];
    ushort s0 = f2bf(v);
    float r1 = v - bf2f(s0);
    ushort s1 = f2bf(r1);
    float r2 = r1 - bf2f(s1);
    ushort s2 = f2bf(r2);
    constexpr size_t SS = (size_t)128 * 1024 * 32;
    size_t b = ((size_t)(kp >> 5) * 1024 + j) * 32 + (kp & 31);
    dst[b] = s0; dst[b + SS] = s1; dst[b + 2 * SS] = s2;
}

// ------------------------------------------------------------ conv1 (fp32) --
// NCHW input -> NHWC fp32 static
__global__ __launch_bounds__(256) void conv1_k(const float* __restrict__ inp,
                                               const float* __restrict__ w1,
                                               float* __restrict__ stat) {
    __shared__ float ws[1728];
    int tid = threadIdx.x;
    for (int e = tid; e < 1728; e += 256) ws[e] = w1[e];
    __syncthreads();
    int m = blockIdx.x * 256 + tid;
    int n = m >> 10, h = (m >> 5) & 31, w = m & 31;
    float wv[27];
#pragma unroll
    for (int ic = 0; ic < 3; ++ic)
#pragma unroll
        for (int kh = 0; kh < 3; ++kh)
#pragma unroll
            for (int kw = 0; kw < 3; ++kw) {
                int r = h + kh - 1, c = w + kw - 1;
                wv[ic * 9 + kh * 3 + kw] =
                    (r >= 0 && r < 32 && c >= 0 && c < 32)
                        ? inp[(n * 3 + ic) * 1024 + r * 32 + c] : 0.0f;
            }
    for (int oc = 0; oc < 64; oc += 4) {
        float a0 = 0, a1 = 0, a2 = 0, a3 = 0;
#pragma unroll
        for (int j = 0; j < 27; ++j) {
            float x = wv[j];
            a0 += ws[(oc + 0) * 27 + j] * x;
            a1 += ws[(oc + 1) * 27 + j] * x;
            a2 += ws[(oc + 2) * 27 + j] * x;
            a3 += ws[(oc + 3) * 27 + j] * x;
        }
        *(float4*)&stat[(size_t)m * 64 + oc] = make_float4(a0, a1, a2, a3);
    }
}

// ---------------------------------------------------------------- LIF0 ----
// static/mem0 fp32 NHWC compact; spikes -> padded act1 interior (bf16)
__global__ void lif0_k(const float* __restrict__ stat, float* __restrict__ mem,
                       ushort* __restrict__ act1) {
    int i = blockIdx.x * 256 + threadIdx.x;   // 2,097,152 float4 units
    float4 s = ((const float4*)stat)[i];
    float4 m = ((float4*)mem)[i];
    float p0, p1, p2, p3;
    m.x = 0.05f * m.x + 0.95f * s.x; p0 = (m.x > 1.f) ? 1.f : 0.f; m.x -= p0;
    m.y = 0.05f * m.y + 0.95f * s.y; p1 = (m.y > 1.f) ? 1.f : 0.f; m.y -= p1;
    m.z = 0.05f * m.z + 0.95f * s.z; p2 = (m.z > 1.f) ? 1.f : 0.f; m.z -= p2;
    m.w = 0.05f * m.w + 0.95f * s.w; p3 = (m.w > 1.f) ? 1.f : 0.f; m.w -= p3;
    ((float4*)mem)[i] = m;
    int e = i * 4;
    int c = e & 63, w = (e >> 6) & 31, h = (e >> 11) & 31, n = e >> 16;
    size_t d = ((size_t)(n * 34 + h + 1) * 34 + (w + 1)) * 64 + c;
    short4 o;
    o.x = p0 > 0.f ? (short)0x3F80 : 0;
    o.y = p1 > 0.f ? (short)0x3F80 : 0;
    o.z = p2 > 0.f ? (short)0x3F80 : 0;
    o.w = p3 > 0.f ? (short)0x3F80 : 0;
    *(short4*)&act1[d] = o;
}

// --------------------------------------------------- implicit-GEMM conv ----
// act: padded NHWC bf16 [n][H+2][W+2][IC]; wp: [s][q][icb][oc][32]
// out: spikes bf16, padded interior (PADOUT) or compact NHWC
template <int H, int W, int IC, int OC, int MBLK, bool PADOUT>
__global__ __launch_bounds__(256) void convmm_k(const ushort* __restrict__ act,
                                                const ushort* __restrict__ wp,
                                                ushort* __restrict__ out) {
    constexpr int ICB = IC / 32, PWd = W + 2, LW = 40;
    constexpr int AM = MBLK / 32;      // 16-row frags per wave (2x2 wave grid)
    constexpr int ACH = MBLK / 64;     // 16B staging chunks per thread
    constexpr int LHW = ilog2(H * W), LWl = ilog2(W);
    __shared__ ushort sA[MBLK * LW];
    __shared__ ushort sB[192 * LW];

    const int tid = threadIdx.x, lane = tid & 63, wid = tid >> 6;
    const int wm = wid >> 1, wn = wid & 1;
    const int m0 = blockIdx.x * MBLK, oc0 = blockIdx.y * 64;

    int rowbase[ACH], ldsA[ACH];
#pragma unroll
    for (int i = 0; i < ACH; ++i) {
        int idx = i * 256 + tid;
        int r = idx >> 2, c = idx & 3;
        int m = m0 + r;
        int n = m >> LHW, h = (m >> LWl) & (H - 1), w = m & (W - 1);
        rowbase[i] = ((n * (H + 2) + h) * PWd + w) * IC + c * 8;
        ldsA[i] = r * LW + c * 8;
    }
    int pB[3], ldsB[3];
    {
        int oc = tid >> 2, c = tid & 3;
#pragma unroll
        for (int j = 0; j < 3; ++j) {
            pB[j] = j * (9 * ICB * OC * 32) + (oc0 + oc) * 32 + c * 8;
            ldsB[j] = (j * 64 + oc) * LW + c * 8;
        }
    }

    f32x4 acc[AM][2];
#pragma unroll
    for (int a = 0; a < AM; ++a)
#pragma unroll
        for (int b = 0; b < 2; ++b) acc[a][b] = (f32x4){0.f, 0.f, 0.f, 0.f};

    for (int q = 0; q < 9; ++q) {
        const int khw = ((q / 3) * PWd + (q % 3)) * IC;
        for (int icb = 0; icb < ICB; ++icb) {
            __syncthreads();
#pragma unroll
            for (int i = 0; i < ACH; ++i)
                *(short8v*)&sA[ldsA[i]] =
                    *(const short8v*)&act[rowbase[i] + khw + icb * 32];
            const int qq = (q * ICB + icb) * (OC * 32);
#pragma unroll
            for (int j = 0; j < 3; ++j)
                *(short8v*)&sB[ldsB[j]] = *(const short8v*)&wp[pB[j] + qq];
            __syncthreads();

            short8v af[AM];
#pragma unroll
            for (int am = 0; am < AM; ++am)
                af[am] = *(const short8v*)&sA[(wm * (MBLK / 2) + am * 16 + (lane & 15)) * LW + (lane >> 4) * 8];
#pragma unroll
            for (int s = 0; s < 3; ++s) {
                short8v b0 = *(const short8v*)&sB[(s * 64 + wn * 32 + (lane & 15)) * LW + (lane >> 4) * 8];
                short8v b1 = *(const short8v*)&sB[(s * 64 + wn * 32 + 16 + (lane & 15)) * LW + (lane >> 4) * 8];
#pragma unroll
                for (int am = 0; am < AM; ++am) {
                    acc[am][0] = __builtin_amdgcn_mfma_f32_16x16x32_bf16(af[am], b0, acc[am][0], 0, 0, 0);
                    acc[am][1] = __builtin_amdgcn_mfma_f32_16x16x32_bf16(af[am], b1, acc[am][1], 0, 0, 0);
                }
            }
        }
    }

#pragma unroll
    for (int am = 0; am < AM; ++am)
#pragma unroll
        for (int bn = 0; bn < 2; ++bn)
#pragma unroll
            for (int rr = 0; rr < 4; ++rr) {
                int rl = wm * (MBLK / 2) + am * 16 + (lane >> 4) * 4 + rr;
                int col = oc0 + wn * 32 + bn * 16 + (lane & 15);
                int m = m0 + rl;
                int n = m >> LHW, h = (m >> LWl) & (H - 1), w = m & (W - 1);
                float v = acc[am][bn][rr];
                ushort sp = (v > 1.0f) ? (ushort)0x3F80 : (ushort)0;
                size_t a = PADOUT
                    ? ((size_t)(n * (H + 2) + h + 1) * PWd + (w + 1)) * OC + col
                    : (size_t)m * OC + col;
                out[a] = sp;
            }
}

// ---------------------------------------------------------------- pool ----
template <int C, int HI, bool PADO>
__global__ void pool_k(const ushort* __restrict__ in, ushort* __restrict__ out) {
    constexpr int HO = HI / 2, C8 = C / 8;
    constexpr int TOT = 128 * HO * HO * C8;
    int idx = blockIdx.x * 256 + threadIdx.x;
    if (idx >= TOT) return;
    int c8 = idx % C8;
    int t = idx / C8;
    int w = t % HO; t /= HO;
    int h = t % HO;
    int n = t / HO;
    const ushort* p = in + ((size_t)(n * HI + 2 * h) * HI + 2 * w) * C + c8 * 8;
    short8v v00 = *(const short8v*)p;
    short8v v01 = *(const short8v*)(p + C);
    short8v v10 = *(const short8v*)(p + (size_t)HI * C);
    short8v v11 = *(const short8v*)(p + (size_t)HI * C + C);
    short8v r;
#pragma unroll
    for (int e = 0; e < 8; ++e) {
        float s = bf2f((ushort)v00[e]) + bf2f((ushort)v01[e]) +
                  bf2f((ushort)v10[e]) + bf2f((ushort)v11[e]);
        r[e] = (short)f2bf(s * 0.25f);
    }
    size_t a = PADO
        ? ((size_t)(n * (HO + 2) + h + 1) * (HO + 2) + (w + 1)) * C + c8 * 8
        : (size_t)idx * 8;
    *(short8v*)&out[a] = r;
}

// ----------------------------------------------------------- fc1 GEMM ----
// A [128][4096] bf16, wp [s][kb][j][32], part [32][128][1024] fp32
__global__ __launch_bounds__(256) void fc1mm_k(const ushort* __restrict__ A,
                                               const ushort* __restrict__ wp,
                                               float* __restrict__ part) {
    constexpr int LW = 40;
    __shared__ ushort sA[128 * LW];
    __shared__ ushort sB[64 * LW];
    const int tid = threadIdx.x, lane = tid & 63, wid = tid >> 6;
    const int wm = wid >> 1, wn = wid & 1;
    const int j0 = blockIdx.x * 64, kt = blockIdx.y;

    int rbase[2], ldsA[2];
#pragma unroll
    for (int i = 0; i < 2; ++i) {
        int idx = i * 256 + tid;
        int r = idx >> 2, c = idx & 3;
        rbase[i] = r * 4096 + c * 8;
        ldsA[i] = r * LW + c * 8;
    }
    const int ocl = tid >> 2, cB = tid & 3;
    const int ldsBo = ocl * LW + cB * 8;

    f32x4 acc[4][2];
#pragma unroll
    for (int a = 0; a < 4; ++a)
#pragma unroll
        for (int b = 0; b < 2; ++b) acc[a][b] = (f32x4){0.f, 0.f, 0.f, 0.f};

    for (int st = 0; st < 12; ++st) {
        int k0 = kt * 384 + st * 32;
        int s = k0 >> 12, kk = k0 & 4095;
        __syncthreads();
#pragma unroll
        for (int i = 0; i < 2; ++i)
            *(short8v*)&sA[ldsA[i]] = *(const short8v*)&A[rbase[i] + kk];
        *(short8v*)&sB[ldsBo] =
            *(const short8v*)&wp[(((size_t)s * 128 + (kk >> 5)) * 1024 + j0 + ocl) * 32 + cB * 8];
        __syncthreads();
        short8v af[4];
#pragma unroll
        for (int am = 0; am < 4; ++am)
            af[am] = *(const short8v*)&sA[(wm * 64 + am * 16 + (lane & 15)) * LW + (lane >> 4) * 8];
        short8v b0 = *(const short8v*)&sB[(wn * 32 + (lane & 15)) * LW + (lane >> 4) * 8];
        short8v b1 = *(const short8v*)&sB[(wn * 32 + 16 + (lane & 15)) * LW + (lane >> 4) * 8];
#pragma unroll
        for (int am = 0; am < 4; ++am) {
            acc[am][0] = __builtin_amdgcn_mfma_f32_16x16x32_bf16(af[am], b0, acc[am][0], 0, 0, 0);
            acc[am][1] = __builtin_amdgcn_mfma_f32_16x16x32_bf16(af[am], b1, acc[am][1], 0, 0, 0);
        }
    }
#pragma unroll
    for (int am = 0; am < 4; ++am)
#pragma unroll
        for (int bn = 0; bn < 2; ++bn)
#pragma unroll
            for (int rr = 0; rr < 4; ++rr) {
                int row = wm * 64 + am * 16 + (lane >> 4) * 4 + rr;
                int col = j0 + wn * 32 + bn * 16 + (lane & 15);
                part[((size_t)kt * 128 + row) * 1024 + col] = acc[am][bn][rr];
            }
}

// reduce split-K partials + LIF + spike (bf16)
__global__ void fc1red_k(const float* __restrict__ part, float* __restrict__ mem,
                         ushort* __restrict__ sbuf) {
    int idx = blockIdx.x * 256 + threadIdx.x;   // 131072
    float y = 0.f;
#pragma unroll
    for (int kt = 0; kt < 32; ++kt) y += part[(size_t)kt * 131072 + idx];
    float m = mem[idx];
    m = 0.05f * m + 0.95f * y;
    float sp = (m > 1.f) ? 1.f : 0.f;
    m -= sp;
    mem[idx] = m;
    sbuf[idx] = sp > 0.f ? (ushort)0x3F80 : (ushort)0;
}

// mem_fc2[n][o] += sum_j S[n][j]*W2[o][j]
__global__ __launch_bounds__(256) void fc2_k(const ushort* __restrict__ S,
                                             const float* __restrict__ W2,
                                             float* __restrict__ memfc2) {
    int n = blockIdx.x, tid = threadIdx.x;
    __shared__ float red[10][256];
    const ushort* sp = S + (size_t)n * 1024 + tid * 4;
    float s0 = bf2f(sp[0]), s1 = bf2f(sp[1]), s2 = bf2f(sp[2]), s3 = bf2f(sp[3]);
#pragma unroll
    for (int o = 0; o < 10; ++o) {
        const float* w = W2 + (size_t)o * 1024 + tid * 4;
        red[o][tid] = s0 * w[0] + s1 * w[1] + s2 * w[2] + s3 * w[3];
    }
    __syncthreads();
    for (int off = 128; off >= 1; off >>= 1) {
        if (tid < off) {
#pragma unroll
            for (int o = 0; o < 10; ++o) red[o][tid] += red[o][tid + off];
        }
        __syncthreads();
    }
    if (tid < 10) memfc2[n * 10 + tid] += red[tid][0];
}

__global__ void finalize_k(const float* __restrict__ memfc2, float* __restrict__ out, int n) {
    int i = blockIdx.x * blockDim.x + threadIdx.x;
    if (i < n) out[i] = memfc2[i] * 0.1f;
}

// ---------------------------------------------------------------------------
extern "C" void kernel_launch(void* const* d_in, const int* in_sizes, int n_in,
                              void* d_out, int out_size, void* d_ws, size_t ws_size,
                              hipStream_t stream) {
    const float* inp  = (const float*)d_in[0];
    const float* w1   = (const float*)d_in[1];
    const float* w2   = (const float*)d_in[2];
    const float* w3   = (const float*)d_in[3];
    const float* w4   = (const float*)d_in[4];
    const float* w5   = (const float*)d_in[5];
    const float* w6   = (const float*)d_in[6];
    const float* w7   = (const float*)d_in[7];
    const float* fc1w = (const float*)d_in[8];
    const float* fc2w = (const float*)d_in[9];
    float* out = (float*)d_out;

    char* base = (char*)d_ws;
    size_t o = 0;
    auto alloc = [&](size_t bytes) { void* p = base + o; o += (bytes + 255) & ~(size_t)255; return p; };

    // ---- zeroed region (membranes + padded spike buffers with halos) ----
    float*  mem0  = (float*)alloc(33554432);     // [128][32][32][64] f32 NHWC
    float*  memf1 = (float*)alloc(524288);       // [128][1024] f32
    float*  memf2 = (float*)alloc(5120);         // [128][10] f32
    ushort* act1  = (ushort*)alloc(18939904);    // [128][34][34][64]
    ushort* act2  = (ushort*)alloc(5308416);     // [128][18][18][64]
    ushort* c3out = (ushort*)alloc(10616832);    // [128][18][18][128]
    ushort* act3  = (ushort*)alloc(3276800);     // [128][10][10][128]
    ushort* c5out = (ushort*)alloc(6553600);     // [128][10][10][256]
    ushort* c6out = (ushort*)alloc(6553600);     // [128][10][10][256]
    const size_t zero_bytes = 85332992;          // mem0 .. c6out inclusive
    // ---- non-zeroed ----
    float*  stat  = (float*)alloc(33554432);     // conv1 out, NHWC f32
    char*   bufC  = (char*)alloc(16777216);      // c2out/c4out/c7out bf16 | fc1 partials f32
    ushort* afc1  = (ushort*)alloc(1048576);     // [128][4096] bf16
    ushort* sbuf  = (ushort*)alloc(262144);      // [128][1024] bf16
    ushort* wp2   = (ushort*)alloc(221184);
    ushort* wp3   = (ushort*)alloc(442368);
    ushort* wp4   = (ushort*)alloc(884736);
    ushort* wp5   = (ushort*)alloc(1769472);
    ushort* wp6   = (ushort*)alloc(3538944);
    ushort* wp7   = (ushort*)alloc(3538944);
    ushort* wpf1  = (ushort*)alloc(25165824);
    (void)ws_size;

    // zero membranes + halo buffers (one pass)
    {
        int n4 = (int)(zero_bytes / 16);
        zero4_k<<<(n4 + 255) / 256, 256, 0, stream>>>((float4*)mem0, n4);
    }
    // weight prep (every call; deterministic)
    prep_convw_k<64, 64>  <<<(36864 + 255) / 256, 256, 0, stream>>>(w2, wp2);
    prep_convw_k<64, 128> <<<(73728 + 255) / 256, 256, 0, stream>>>(w3, wp3);
    prep_convw_k<128, 128><<<(147456 + 255) / 256, 256, 0, stream>>>(w4, wp4);
    prep_convw_k<128, 256><<<(294912 + 255) / 256, 256, 0, stream>>>(w5, wp5);
    prep_convw_k<256, 256><<<(589824 + 255) / 256, 256, 0, stream>>>(w6, wp6);
    prep_convw_k<256, 256><<<(589824 + 255) / 256, 256, 0, stream>>>(w7, wp7);
    prep_fc1w_k<<<(4194304 + 255) / 256, 256, 0, stream>>>(fc1w, wpf1);

    conv1_k<<<512, 256, 0, stream>>>(inp, w1, stat);

    for (int t = 0; t < 10; ++t) {
        lif0_k<<<8192, 256, 0, stream>>>(stat, mem0, act1);

        convmm_k<32, 32, 64, 64, 128, false>
            <<<dim3(1024, 1), 256, 0, stream>>>(act1, wp2, (ushort*)bufC);
        pool_k<64, 32, true><<<1024, 256, 0, stream>>>((ushort*)bufC, act2);

        convmm_k<16, 16, 64, 128, 128, true>
            <<<dim3(256, 2), 256, 0, stream>>>(act2, wp3, c3out);
        convmm_k<16, 16, 128, 128, 128, false>
            <<<dim3(256, 2), 256, 0, stream>>>(c3out, wp4, (ushort*)bufC);
        pool_k<128, 16, true><<<512, 256, 0, stream>>>((ushort*)bufC, act3);

        convmm_k<8, 8, 128, 256, 64, true>
            <<<dim3(128, 4), 256, 0, stream>>>(act3, wp5, c5out);
        convmm_k<8, 8, 256, 256, 64, true>
            <<<dim3(128, 4), 256, 0, stream>>>(c5out, wp6, c6out);
        convmm_k<8, 8, 256, 256, 64, false>
            <<<dim3(128, 4), 256, 0, stream>>>(c6out, wp7, (ushort*)bufC);
        pool_k<256, 8, false><<<256, 256, 0, stream>>>((ushort*)bufC, afc1);

        fc1mm_k<<<dim3(16, 32), 256, 0, stream>>>(afc1, wpf1, (float*)bufC);
        fc1red_k<<<512, 256, 0, stream>>>((const float*)bufC, memf1, sbuf);
        fc2_k<<<128, 256, 0, stream>>>(sbuf, fc2w, memf2);
    }

    finalize_k<<<(1280 + 255) / 256, 256, 0, stream>>>(memf2, out, 1280);
}

// Round 3
// 2060.434 us; speedup vs baseline: 16.5051x; 1.4417x over previous
//
#include <hip/hip_runtime.h>

// ---------------------------------------------------------------------------
// Spiking VGG9, 10 steps, B=128.  R3: conv rewrite
//  - global_load_lds(16B) staging, BK=64 (128B LDS rows), XOR swizzle
//    (A: source-side gather swizzle; B: pre-swizzled at weight-pack time)
//  - tiles: conv2 256x64, conv3..7 128x64; split-K=2 for the 8x8 convs
//  - 3-way bf16 weight split (fp32-exact), spikes exact in bf16
// ---------------------------------------------------------------------------

typedef __attribute__((ext_vector_type(8))) short short8v;
typedef __attribute__((ext_vector_type(4))) float f32x4;

__device__ __forceinline__ ushort f2bf(float f) {
    union { float f; unsigned u; } v; v.f = f;
    unsigned u = v.u;
    u += 0x7fffu + ((u >> 16) & 1u);   // RNE
    return (ushort)(u >> 16);
}
__device__ __forceinline__ float bf2f(ushort h) {
    union { unsigned u; float f; } v; v.u = ((unsigned)h) << 16;
    return v.f;
}
constexpr int ilog2(int x) { int r = 0; while (x > 1) { x >>= 1; ++r; } return r; }

__device__ __forceinline__ void gl_lds16(const ushort* g, ushort* l) {
    __builtin_amdgcn_global_load_lds(
        (const __attribute__((address_space(1))) unsigned int*)g,
        (__attribute__((address_space(3))) unsigned int*)l, 16, 0, 0);
}

// ---------------------------------------------------------------- zero ----
__global__ void zero4_k(float4* __restrict__ p, int n4) {
    int i = blockIdx.x * 256 + threadIdx.x;
    if (i < n4) p[i] = make_float4(0.f, 0.f, 0.f, 0.f);
}

// ------------------------------------------------------------ weight prep --
// conv weights OIHW fp32 -> wq[kstep][oc_tile][3*NBLK][64k], pre-swizzled:
// element (R, c-chunk) stored at chunk c ^ (R&7).
template <int IC, int OC, int NBLK>
__global__ void prep_convw_k(const float* __restrict__ w, ushort* __restrict__ dst) {
    int idx = blockIdx.x * 256 + threadIdx.x;
    if (idx >= OC * IC * 9) return;
    int oc = idx / (IC * 9);
    int rem = idx % (IC * 9);
    int ic = rem / 9, q = rem % 9;
    float v = w[idx];
    ushort s0 = f2bf(v);
    float r1 = v - bf2f(s0);
    ushort s1 = f2bf(r1);
    float r2 = r1 - bf2f(s1);
    ushort s2 = f2bf(r2);
    constexpr int ICP = IC / 64;
    int ks = q * ICP + (ic >> 6);
    int kin = ic & 63;
    int cc = kin >> 3, ee = kin & 7;
    int oct = oc / NBLK, ocl = oc % NBLK;
    size_t base = ((size_t)ks * (OC / NBLK) + oct) * (3 * NBLK * 64);
    ushort vals[3] = {s0, s1, s2};
#pragma unroll
    for (int s = 0; s < 3; ++s) {
        int R = s * NBLK + ocl;
        int cp = cc ^ (R & 7);
        dst[base + (size_t)R * 64 + cp * 8 + ee] = vals[s];
    }
}

// fc1 weights [1024][4096] fp32, cols k=(c*16+h*4+w) -> k'=(h*4+w)*256+c,
// pack [s][kb(128)][j(1024)][32]
__global__ void prep_fc1w_k(const float* __restrict__ w, ushort* __restrict__ dst) {
    int idx = blockIdx.x * 256 + threadIdx.x;
    if (idx >= 1024 * 4096) return;
    int j = idx >> 12, k = idx & 4095;
    int c = k >> 4, hw = k & 15;
    int kp = hw * 256 + c;
    float v = w[idx];
    ushort s0 = f2bf(v);
    float r1 = v - bf2f(s0);
    ushort s1 = f2bf(r1);
    float r2 = r1 - bf2f(s1);
    ushort s2 = f2bf(r2);
    constexpr size_t SS = (size_t)128 * 1024 * 32;
    size_t b = ((size_t)(kp >> 5) * 1024 + j) * 32 + (kp & 31);
    dst[b] = s0; dst[b + SS] = s1; dst[b + 2 * SS] = s2;
}

// ------------------------------------------------------------ conv1 (fp32) --
__global__ __launch_bounds__(256) void conv1_k(const float* __restrict__ inp,
                                               const float* __restrict__ w1,
                                               float* __restrict__ stat) {
    __shared__ float ws[1728];
    int tid = threadIdx.x;
    for (int e = tid; e < 1728; e += 256) ws[e] = w1[e];
    __syncthreads();
    int m = blockIdx.x * 256 + tid;
    int n = m >> 10, h = (m >> 5) & 31, w = m & 31;
    float wv[27];
#pragma unroll
    for (int ic = 0; ic < 3; ++ic)
#pragma unroll
        for (int kh = 0; kh < 3; ++kh)
#pragma unroll
            for (int kw = 0; kw < 3; ++kw) {
                int r = h + kh - 1, c = w + kw - 1;
                wv[ic * 9 + kh * 3 + kw] =
                    (r >= 0 && r < 32 && c >= 0 && c < 32)
                        ? inp[(n * 3 + ic) * 1024 + r * 32 + c] : 0.0f;
            }
    for (int oc = 0; oc < 64; oc += 4) {
        float a0 = 0, a1 = 0, a2 = 0, a3 = 0;
#pragma unroll
        for (int j = 0; j < 27; ++j) {
            float x = wv[j];
            a0 += ws[(oc + 0) * 27 + j] * x;
            a1 += ws[(oc + 1) * 27 + j] * x;
            a2 += ws[(oc + 2) * 27 + j] * x;
            a3 += ws[(oc + 3) * 27 + j] * x;
        }
        *(float4*)&stat[(size_t)m * 64 + oc] = make_float4(a0, a1, a2, a3);
    }
}

// ---------------------------------------------------------------- LIF0 ----
__global__ void lif0_k(const float* __restrict__ stat, float* __restrict__ mem,
                       ushort* __restrict__ act1) {
    int i = blockIdx.x * 256 + threadIdx.x;   // 2,097,152 float4 units
    float4 s = ((const float4*)stat)[i];
    float4 m = ((float4*)mem)[i];
    float p0, p1, p2, p3;
    m.x = 0.05f * m.x + 0.95f * s.x; p0 = (m.x > 1.f) ? 1.f : 0.f; m.x -= p0;
    m.y = 0.05f * m.y + 0.95f * s.y; p1 = (m.y > 1.f) ? 1.f : 0.f; m.y -= p1;
    m.z = 0.05f * m.z + 0.95f * s.z; p2 = (m.z > 1.f) ? 1.f : 0.f; m.z -= p2;
    m.w = 0.05f * m.w + 0.95f * s.w; p3 = (m.w > 1.f) ? 1.f : 0.f; m.w -= p3;
    ((float4*)mem)[i] = m;
    int e = i * 4;
    int c = e & 63, w = (e >> 6) & 31, h = (e >> 11) & 31, n = e >> 16;
    size_t d = ((size_t)(n * 34 + h + 1) * 34 + (w + 1)) * 64 + c;
    short4 o;
    o.x = p0 > 0.f ? (short)0x3F80 : 0;
    o.y = p1 > 0.f ? (short)0x3F80 : 0;
    o.z = p2 > 0.f ? (short)0x3F80 : 0;
    o.w = p3 > 0.f ? (short)0x3F80 : 0;
    *(short4*)&act1[d] = o;
}

// --------------------------------------------------- implicit-GEMM conv ----
// act: padded NHWC bf16 [n][H+2][W+2][IC]
// wq : [kstep][oc_tile][3*NBLK][64] pre-swizzled
// EPI: 0 = spike compact, 1 = spike padded, 2 = fp32 split-K partial
template <int H, int W, int IC, int OC, int MBLK, int NBLK, int KT, int EPI>
__global__ __launch_bounds__(256) void convmm_k(const ushort* __restrict__ act,
                                                const ushort* __restrict__ wq,
                                                ushort* __restrict__ outs,
                                                float* __restrict__ outp) {
    constexpr int PWd = W + 2;
    constexpr int KS = 9 * IC / 64;
    constexpr int ICP = IC / 64;
    constexpr int LHW = ilog2(H * W), LWl = ilog2(W);
    constexpr int AROUNDS = MBLK / 32;
    constexpr int BROUNDS = 3 * NBLK / 32;
    constexpr int WM = MBLK / 2, WN = NBLK / 2;
    constexpr int AM = WM / 16, BN = WN / 16;
    constexpr size_t WQ_KSTRIDE = (size_t)(OC / NBLK) * 3 * NBLK * 64;

    __shared__ __align__(16) ushort sA[MBLK * 64];
    __shared__ __align__(16) ushort sB[3 * NBLK * 64];

    const int tid = threadIdx.x, lane = tid & 63;
    const int wid = tid >> 6, wm = wid >> 1, wn = wid & 1;
    const int m0 = blockIdx.x * MBLK, oc0 = blockIdx.y * NBLK;
    const int kt = blockIdx.z;
    const int ks0 = KS * kt / KT, ks1 = KS * (kt + 1) / KT;

    // A staging: row r = tid>>3 (+32/round), source chunk swizzled by r&7
    const int ar = tid >> 3;
    const int acg = (tid & 7) ^ (ar & 7);
    int arow[AROUNDS];
#pragma unroll
    for (int i = 0; i < AROUNDS; ++i) {
        int m = m0 + i * 32 + ar;
        int n = m >> LHW, h = (m >> LWl) & (H - 1), w = m & (W - 1);
        arow[i] = ((n * (H + 2) + h) * PWd + w) * IC + acg * 8;
    }
    const ushort* wqt = wq + (size_t)(oc0 / NBLK) * (3 * NBLK * 64);

    f32x4 acc[AM][BN];
#pragma unroll
    for (int a = 0; a < AM; ++a)
#pragma unroll
        for (int b = 0; b < BN; ++b) acc[a][b] = (f32x4){0.f, 0.f, 0.f, 0.f};

    for (int ks = ks0; ks < ks1; ++ks) {
        const int q = ks / ICP, icp = ks % ICP;
        const int koff = ((q / 3) * PWd + (q % 3)) * IC + icp * 64;
        __syncthreads();
#pragma unroll
        for (int i = 0; i < AROUNDS; ++i)
            gl_lds16(act + arow[i] + koff, sA + i * 2048 + tid * 8);
        const ushort* wk = wqt + (size_t)ks * WQ_KSTRIDE;
#pragma unroll
        for (int i = 0; i < BROUNDS; ++i)
            gl_lds16(wk + i * 2048 + tid * 8, sB + i * 2048 + tid * 8);
        __syncthreads();

#pragma unroll
        for (int kh = 0; kh < 2; ++kh) {
            const int c = kh * 4 + (lane >> 4);
            short8v af[AM];
#pragma unroll
            for (int am = 0; am < AM; ++am) {
                int r = wm * WM + am * 16 + (lane & 15);
                af[am] = *(const short8v*)&sA[r * 64 + ((c ^ (r & 7)) << 3)];
            }
#pragma unroll
            for (int s = 0; s < 3; ++s)
#pragma unroll
                for (int bn = 0; bn < BN; ++bn) {
                    int R = s * NBLK + wn * WN + bn * 16 + (lane & 15);
                    short8v bf = *(const short8v*)&sB[R * 64 + ((c ^ (R & 7)) << 3)];
#pragma unroll
                    for (int am = 0; am < AM; ++am)
                        acc[am][bn] = __builtin_amdgcn_mfma_f32_16x16x32_bf16(
                            af[am], bf, acc[am][bn], 0, 0, 0);
                }
        }
    }

    constexpr size_t MTOT = (size_t)128 * H * W;
#pragma unroll
    for (int am = 0; am < AM; ++am)
#pragma unroll
        for (int bn = 0; bn < BN; ++bn)
#pragma unroll
            for (int rr = 0; rr < 4; ++rr) {
                int rl = wm * WM + am * 16 + (lane >> 4) * 4 + rr;
                int col = oc0 + wn * WN + bn * 16 + (lane & 15);
                int m = m0 + rl;
                float v = acc[am][bn][rr];
                if (EPI == 2) {
                    outp[((size_t)kt * MTOT + m) * OC + col] = v;
                } else {
                    ushort sp = (v > 1.0f) ? (ushort)0x3F80 : (ushort)0;
                    if (EPI == 1) {
                        int n = m >> LHW, h = (m >> LWl) & (H - 1), w = m & (W - 1);
                        outs[((size_t)(n * (H + 2) + h + 1) * PWd + (w + 1)) * OC + col] = sp;
                    } else {
                        outs[(size_t)m * OC + col] = sp;
                    }
                }
            }
}

// ---------------------------------------------- split-K combine (+spike) ----
// part: [2][128*H*H][OC] fp32 -> spikes bf16 padded interior
template <int H, int OC>
__global__ void combine_k(const float* __restrict__ part, ushort* __restrict__ out) {
    constexpr size_t MTOT = (size_t)128 * H * H;
    constexpr size_t TOT = MTOT * OC;
    constexpr int LH = ilog2(H);
    size_t i = ((size_t)blockIdx.x * 256 + threadIdx.x) * 4;
    if (i >= TOT) return;
    float4 a = *(const float4*)&part[i];
    float4 b = *(const float4*)&part[TOT + i];
    short4 o;
    o.x = (a.x + b.x > 1.f) ? (short)0x3F80 : 0;
    o.y = (a.y + b.y > 1.f) ? (short)0x3F80 : 0;
    o.z = (a.z + b.z > 1.f) ? (short)0x3F80 : 0;
    o.w = (a.w + b.w > 1.f) ? (short)0x3F80 : 0;
    int m = (int)(i / OC), c = (int)(i % OC);
    int n = m >> (2 * LH), h = (m >> LH) & (H - 1), w = m & (H - 1);
    *(short4*)&out[((size_t)(n * (H + 2) + h + 1) * (H + 2) + (w + 1)) * OC + c] = o;
}

// conv7 combine fused with 2x2 avgpool -> afc1 [128][4][4][256] bf16
__global__ void comb7pool_k(const float* __restrict__ part, ushort* __restrict__ out) {
    int idx = blockIdx.x * 256 + threadIdx.x;   // 131072
    int c4 = idx & 63;
    int t = idx >> 6;
    int wo = t & 3, ho = (t >> 2) & 3, n = t >> 4;
    int c = c4 * 4;
    float4 s = {0.f, 0.f, 0.f, 0.f};
#pragma unroll
    for (int dh = 0; dh < 2; ++dh)
#pragma unroll
        for (int dw = 0; dw < 2; ++dw) {
            int m = (n * 8 + 2 * ho + dh) * 8 + 2 * wo + dw;
            float4 a = *(const float4*)&part[(size_t)m * 256 + c];
            float4 b = *(const float4*)&part[(size_t)(8192 + m) * 256 + c];
            s.x += (a.x + b.x > 1.f) ? 1.f : 0.f;
            s.y += (a.y + b.y > 1.f) ? 1.f : 0.f;
            s.z += (a.z + b.z > 1.f) ? 1.f : 0.f;
            s.w += (a.w + b.w > 1.f) ? 1.f : 0.f;
        }
    short4 o;
    o.x = (short)f2bf(s.x * 0.25f);
    o.y = (short)f2bf(s.y * 0.25f);
    o.z = (short)f2bf(s.z * 0.25f);
    o.w = (short)f2bf(s.w * 0.25f);
    *(short4*)&out[(size_t)idx * 4] = o;
}

// ---------------------------------------------------------------- pool ----
template <int C, int HI, bool PADO>
__global__ void pool_k(const ushort* __restrict__ in, ushort* __restrict__ out) {
    constexpr int HO = HI / 2, C8 = C / 8;
    constexpr int TOT = 128 * HO * HO * C8;
    int idx = blockIdx.x * 256 + threadIdx.x;
    if (idx >= TOT) return;
    int c8 = idx % C8;
    int t = idx / C8;
    int w = t % HO; t /= HO;
    int h = t % HO;
    int n = t / HO;
    const ushort* p = in + ((size_t)(n * HI + 2 * h) * HI + 2 * w) * C + c8 * 8;
    short8v v00 = *(const short8v*)p;
    short8v v01 = *(const short8v*)(p + C);
    short8v v10 = *(const short8v*)(p + (size_t)HI * C);
    short8v v11 = *(const short8v*)(p + (size_t)HI * C + C);
    short8v r;
#pragma unroll
    for (int e = 0; e < 8; ++e) {
        float s = bf2f((ushort)v00[e]) + bf2f((ushort)v01[e]) +
                  bf2f((ushort)v10[e]) + bf2f((ushort)v11[e]);
        r[e] = (short)f2bf(s * 0.25f);
    }
    size_t a = PADO
        ? ((size_t)(n * (HO + 2) + h + 1) * (HO + 2) + (w + 1)) * C + c8 * 8
        : (size_t)idx * 8;
    *(short8v*)&out[a] = r;
}

// ----------------------------------------------------------- fc1 GEMM ----
__global__ __launch_bounds__(256) void fc1mm_k(const ushort* __restrict__ A,
                                               const ushort* __restrict__ wp,
                                               float* __restrict__ part) {
    constexpr int LW = 40;
    __shared__ ushort sA[128 * LW];
    __shared__ ushort sB[64 * LW];
    const int tid = threadIdx.x, lane = tid & 63, wid = tid >> 6;
    const int wm = wid >> 1, wn = wid & 1;
    const int j0 = blockIdx.x * 64, kt = blockIdx.y;

    int rbase[2], ldsA[2];
#pragma unroll
    for (int i = 0; i < 2; ++i) {
        int idx = i * 256 + tid;
        int r = idx >> 2, c = idx & 3;
        rbase[i] = r * 4096 + c * 8;
        ldsA[i] = r * LW + c * 8;
    }
    const int ocl = tid >> 2, cB = tid & 3;
    const int ldsBo = ocl * LW + cB * 8;

    f32x4 acc[4][2];
#pragma unroll
    for (int a = 0; a < 4; ++a)
#pragma unroll
        for (int b = 0; b < 2; ++b) acc[a][b] = (f32x4){0.f, 0.f, 0.f, 0.f};

    for (int st = 0; st < 12; ++st) {
        int k0 = kt * 384 + st * 32;
        int s = k0 >> 12, kk = k0 & 4095;
        __syncthreads();
#pragma unroll
        for (int i = 0; i < 2; ++i)
            *(short8v*)&sA[ldsA[i]] = *(const short8v*)&A[rbase[i] + kk];
        *(short8v*)&sB[ldsBo] =
            *(const short8v*)&wp[(((size_t)s * 128 + (kk >> 5)) * 1024 + j0 + ocl) * 32 + cB * 8];
        __syncthreads();
        short8v af[4];
#pragma unroll
        for (int am = 0; am < 4; ++am)
            af[am] = *(const short8v*)&sA[(wm * 64 + am * 16 + (lane & 15)) * LW + (lane >> 4) * 8];
        short8v b0 = *(const short8v*)&sB[(wn * 32 + (lane & 15)) * LW + (lane >> 4) * 8];
        short8v b1 = *(const short8v*)&sB[(wn * 32 + 16 + (lane & 15)) * LW + (lane >> 4) * 8];
#pragma unroll
        for (int am = 0; am < 4; ++am) {
            acc[am][0] = __builtin_amdgcn_mfma_f32_16x16x32_bf16(af[am], b0, acc[am][0], 0, 0, 0);
            acc[am][1] = __builtin_amdgcn_mfma_f32_16x16x32_bf16(af[am], b1, acc[am][1], 0, 0, 0);
        }
    }
#pragma unroll
    for (int am = 0; am < 4; ++am)
#pragma unroll
        for (int bn = 0; bn < 2; ++bn)
#pragma unroll
            for (int rr = 0; rr < 4; ++rr) {
                int row = wm * 64 + am * 16 + (lane >> 4) * 4 + rr;
                int col = j0 + wn * 32 + bn * 16 + (lane & 15);
                part[((size_t)kt * 128 + row) * 1024 + col] = acc[am][bn][rr];
            }
}

__global__ void fc1red_k(const float* __restrict__ part, float* __restrict__ mem,
                         ushort* __restrict__ sbuf) {
    int idx = blockIdx.x * 256 + threadIdx.x;   // 131072
    float y = 0.f;
#pragma unroll
    for (int kt = 0; kt < 32; ++kt) y += part[(size_t)kt * 131072 + idx];
    float m = mem[idx];
    m = 0.05f * m + 0.95f * y;
    float sp = (m > 1.f) ? 1.f : 0.f;
    m -= sp;
    mem[idx] = m;
    sbuf[idx] = sp > 0.f ? (ushort)0x3F80 : (ushort)0;
}

__global__ __launch_bounds__(256) void fc2_k(const ushort* __restrict__ S,
                                             const float* __restrict__ W2,
                                             float* __restrict__ memfc2) {
    int n = blockIdx.x, tid = threadIdx.x;
    __shared__ float red[10][256];
    const ushort* sp = S + (size_t)n * 1024 + tid * 4;
    float s0 = bf2f(sp[0]), s1 = bf2f(sp[1]), s2 = bf2f(sp[2]), s3 = bf2f(sp[3]);
#pragma unroll
    for (int o = 0; o < 10; ++o) {
        const float* w = W2 + (size_t)o * 1024 + tid * 4;
        red[o][tid] = s0 * w[0] + s1 * w[1] + s2 * w[2] + s3 * w[3];
    }
    __syncthreads();
    for (int off = 128; off >= 1; off >>= 1) {
        if (tid < off) {
#pragma unroll
            for (int o = 0; o < 10; ++o) red[o][tid] += red[o][tid + off];
        }
        __syncthreads();
    }
    if (tid < 10) memfc2[n * 10 + tid] += red[tid][0];
}

__global__ void finalize_k(const float* __restrict__ memfc2, float* __restrict__ out, int n) {
    int i = blockIdx.x * blockDim.x + threadIdx.x;
    if (i < n) out[i] = memfc2[i] * 0.1f;
}

// ---------------------------------------------------------------------------
extern "C" void kernel_launch(void* const* d_in, const int* in_sizes, int n_in,
                              void* d_out, int out_size, void* d_ws, size_t ws_size,
                              hipStream_t stream) {
    const float* inp  = (const float*)d_in[0];
    const float* w1   = (const float*)d_in[1];
    const float* w2   = (const float*)d_in[2];
    const float* w3   = (const float*)d_in[3];
    const float* w4   = (const float*)d_in[4];
    const float* w5   = (const float*)d_in[5];
    const float* w6   = (const float*)d_in[6];
    const float* w7   = (const float*)d_in[7];
    const float* fc1w = (const float*)d_in[8];
    const float* fc2w = (const float*)d_in[9];
    float* out = (float*)d_out;

    char* base = (char*)d_ws;
    size_t o = 0;
    auto alloc = [&](size_t bytes) { void* p = base + o; o += (bytes + 255) & ~(size_t)255; return p; };

    // ---- zeroed region (membranes + padded spike buffers with halos) ----
    float*  mem0  = (float*)alloc(33554432);     // [128][32][32][64] f32 NHWC
    float*  memf1 = (float*)alloc(524288);       // [128][1024] f32
    float*  memf2 = (float*)alloc(5120);         // [128][10] f32
    ushort* act1  = (ushort*)alloc(18939904);    // [128][34][34][64]
    ushort* act2  = (ushort*)alloc(5308416);     // [128][18][18][64]
    ushort* c3out = (ushort*)alloc(10616832);    // [128][18][18][128]
    ushort* act3  = (ushort*)alloc(3276800);     // [128][10][10][128]
    ushort* c5out = (ushort*)alloc(6553600);     // [128][10][10][256]
    ushort* c6out = (ushort*)alloc(6553600);     // [128][10][10][256]
    const size_t zero_bytes = 85332992;          // mem0 .. c6out inclusive
    // ---- non-zeroed ----
    float*  stat  = (float*)alloc(33554432);     // conv1 out, NHWC f32
    char*   bufC  = (char*)alloc(16777216);      // conv2/4 spikes | split-K partials | fc1 partials
    ushort* afc1  = (ushort*)alloc(1048576);     // [128][4][4][256] bf16
    ushort* sbuf  = (ushort*)alloc(262144);      // [128][1024] bf16
    ushort* wq2   = (ushort*)alloc(221184);
    ushort* wq3   = (ushort*)alloc(442368);
    ushort* wq4   = (ushort*)alloc(884736);
    ushort* wq5   = (ushort*)alloc(1769472);
    ushort* wq6   = (ushort*)alloc(3538944);
    ushort* wq7   = (ushort*)alloc(3538944);
    ushort* wpf1  = (ushort*)alloc(25165824);
    (void)ws_size;

    {
        int n4 = (int)(zero_bytes / 16);
        zero4_k<<<(n4 + 255) / 256, 256, 0, stream>>>((float4*)mem0, n4);
    }
    prep_convw_k<64, 64, 64>  <<<(36864 + 255) / 256, 256, 0, stream>>>(w2, wq2);
    prep_convw_k<64, 128, 64> <<<(73728 + 255) / 256, 256, 0, stream>>>(w3, wq3);
    prep_convw_k<128, 128, 64><<<(147456 + 255) / 256, 256, 0, stream>>>(w4, wq4);
    prep_convw_k<128, 256, 64><<<(294912 + 255) / 256, 256, 0, stream>>>(w5, wq5);
    prep_convw_k<256, 256, 64><<<(589824 + 255) / 256, 256, 0, stream>>>(w6, wq6);
    prep_convw_k<256, 256, 64><<<(589824 + 255) / 256, 256, 0, stream>>>(w7, wq7);
    prep_fc1w_k<<<(4194304 + 255) / 256, 256, 0, stream>>>(fc1w, wpf1);

    conv1_k<<<512, 256, 0, stream>>>(inp, w1, stat);

    for (int t = 0; t < 10; ++t) {
        lif0_k<<<8192, 256, 0, stream>>>(stat, mem0, act1);

        convmm_k<32, 32, 64, 64, 256, 64, 1, 0>
            <<<dim3(512, 1, 1), 256, 0, stream>>>(act1, wq2, (ushort*)bufC, nullptr);
        pool_k<64, 32, true><<<1024, 256, 0, stream>>>((ushort*)bufC, act2);

        convmm_k<16, 16, 64, 128, 128, 64, 1, 1>
            <<<dim3(256, 2, 1), 256, 0, stream>>>(act2, wq3, c3out, nullptr);
        convmm_k<16, 16, 128, 128, 128, 64, 1, 0>
            <<<dim3(256, 2, 1), 256, 0, stream>>>(c3out, wq4, (ushort*)bufC, nullptr);
        pool_k<128, 16, true><<<512, 256, 0, stream>>>((ushort*)bufC, act3);

        convmm_k<8, 8, 128, 256, 128, 64, 2, 2>
            <<<dim3(64, 4, 2), 256, 0, stream>>>(act3, wq5, nullptr, (float*)bufC);
        combine_k<8, 256><<<2048, 256, 0, stream>>>((const float*)bufC, c5out);
        convmm_k<8, 8, 256, 256, 128, 64, 2, 2>
            <<<dim3(64, 4, 2), 256, 0, stream>>>(c5out, wq6, nullptr, (float*)bufC);
        combine_k<8, 256><<<2048, 256, 0, stream>>>((const float*)bufC, c6out);
        convmm_k<8, 8, 256, 256, 128, 64, 2, 2>
            <<<dim3(64, 4, 2), 256, 0, stream>>>(c6out, wq7, nullptr, (float*)bufC);
        comb7pool_k<<<512, 256, 0, stream>>>((const float*)bufC, afc1);

        fc1mm_k<<<dim3(16, 32), 256, 0, stream>>>(afc1, wpf1, (float*)bufC);
        fc1red_k<<<512, 256, 0, stream>>>((const float*)bufC, memf1, sbuf);
        fc2_k<<<128, 256, 0, stream>>>(sbuf, fc2w, memf2);
    }

    finalize_k<<<(1280 + 255) / 256, 256, 0, stream>>>(memf2, out, 1280);
}